// Round 8
// baseline (273.654 us; speedup 1.0000x reference)
//
#include <hip/hip_runtime.h>
#include <hip/hip_bf16.h>

typedef unsigned short ushort_t;
typedef __bf16 bf16x8 __attribute__((ext_vector_type(8)));
typedef float f32x4 __attribute__((ext_vector_type(4)));
typedef float f32x8 __attribute__((ext_vector_type(8)));

#define NTOK 1032
#define NROWS 8256       // B*N = 8*1032
#define DIMC 1024
#define QKV_ELEMS 8454144  // 8*16*1032*64 elements per tensor
#define XE 8454144         // X elements (8256*1024)
#define QWE 3145728        // qkv_w elements (3072*1024)
#define OWE 1048576        // out_w elements (1024*1024)

__device__ __forceinline__ float bf2f(ushort_t u) {
    union { unsigned int i; float f; } v; v.i = ((unsigned int)u) << 16; return v.f;
}
__device__ __forceinline__ ushort_t f2bf(float f) {
    union { float f; unsigned int i; } v; v.f = f;
    unsigned int r = v.i + 0x7fffu + ((v.i >> 16) & 1u);
    return (ushort_t)(r >> 16);
}
__device__ __forceinline__ bf16x8 cvt8(const float* p) {
    const float4 a = *(const float4*)p;
    const float4 b = *(const float4*)(p + 4);
    bf16x8 r;
    r[0] = (__bf16)a.x; r[1] = (__bf16)a.y; r[2] = (__bf16)a.z; r[3] = (__bf16)a.w;
    r[4] = (__bf16)b.x; r[5] = (__bf16)b.y; r[6] = (__bf16)b.z; r[7] = (__bf16)b.w;
    return r;
}
__device__ __forceinline__ void load_lds16(const ushort_t* g, ushort_t* l) {
    __builtin_amdgcn_global_load_lds(
        (const __attribute__((address_space(1))) unsigned int*)g,
        (__attribute__((address_space(3))) unsigned int*)l, 16, 0, 0);
}

// ---------------------------------------------------------------------------
// fp32 -> bf16 pre-conversion of X, qkv_w, out_w (RNE).
// ---------------------------------------------------------------------------
__global__ __launch_bounds__(256) void cvt_kernel(
    const float* __restrict__ X, const float* __restrict__ Wq,
    const float* __restrict__ Wo,
    ushort_t* __restrict__ Xb, ushort_t* __restrict__ Wqb,
    ushort_t* __restrict__ Wob)
{
    const long i8 = ((long)blockIdx.x * 256 + threadIdx.x) * 8;
    const float* src;
    ushort_t* dst;
    long off;
    if (i8 < XE)            { src = X;  dst = Xb;  off = i8; }
    else if (i8 < XE + QWE) { src = Wq; dst = Wqb; off = i8 - XE; }
    else                    { src = Wo; dst = Wob; off = i8 - XE - QWE; }
    *(bf16x8*)(dst + off) = cvt8(src + off);
}

// ---------------------------------------------------------------------------
// 256x256 deep-pipelined GEMM body (two named kernels for attribution).
//   MODE 0: QKV projection (nx<8 Q/K swapped + fused norm/rope; nx>=8 V->Vt).
//   MODE 1: out-projection (swap always, fp32 float4 stores), grid 4x33.
// ---------------------------------------------------------------------------
template<int MODE>
__device__ __forceinline__ void gemm256_body(
    const ushort_t* __restrict__ A, const ushort_t* __restrict__ W,
    ushort_t* __restrict__ QKV, float* __restrict__ Out,
    const float* __restrict__ cosb, const float* __restrict__ sinb,
    const float* __restrict__ nqw, const float* __restrict__ nkw)
{
    constexpr int SMEM_BYTES = (MODE == 0) ? 135168 : 131072;
    __shared__ __align__(16) unsigned char SMEM[SMEM_BYTES];
    ushort_t* A_lds = (ushort_t*)SMEM;              // 2 buf x 256 x 64 (64KB)
    ushort_t* B_lds = (ushort_t*)(SMEM + 65536);    // 64KB

    // ---- bijective XCD chunked swizzle (m204) ----
    constexpr int GX  = (MODE == 0) ? 12 : 4;
    constexpr int NWG = GX * 33;
    constexpr int QW  = NWG >> 3, RW = NWG & 7;
    const int orig = blockIdx.y * GX + blockIdx.x;
    const int xcd  = orig & 7, li = orig >> 3;
    const int wgid = (xcd < RW ? xcd * (QW + 1)
                               : RW * (QW + 1) + (xcd - RW) * QW) + li;
    const int bx = wgid % GX, by = wgid / GX;

    const int tid  = threadIdx.x;
    const int wave = tid >> 6, lane = tid & 63;
    const int wr = wave >> 2, wc = wave & 3;        // 2 x 4 wave grid
    const int fr = lane & 15, quad = lane >> 4;
    const int m0 = by * 256;
    const int n0 = bx * 256;
    const bool swap = (MODE == 1) || (bx < 8);

    int aoff[4], boff[4];
    #pragma unroll
    for (int ld = 0; ld < 4; ++ld) {
        const int s   = ld * 512 + tid;
        const int row = s >> 3;
        const int kc  = ((s & 7) ^ (row & 7)) * 8;
        int ar = m0 + row; if (ar > NROWS - 1) ar = NROWS - 1;
        aoff[ld] = ar * DIMC + kc;
        boff[ld] = (n0 + row) * DIMC + kc;
    }

    const int ck0 = (quad ^ (fr & 7)) * 8;          // k-sub 0 (k 0..31)
    const int ck1 = ((quad + 4) ^ (fr & 7)) * 8;    // k-sub 1 (k 32..63)
    const int abase = (wr * 128 + fr) * 64;
    const int bbase = (wc * 64 + fr) * 64;

    f32x4 acc[8][4] = {};

#define SA(ld, t, c) load_lds16(A + aoff[ld] + (t) * 64, \
                                &A_lds[(c) * 16384 + ((ld) * 512 + tid) * 8])
#define SB(ld, t, c) load_lds16(W + boff[ld] + (t) * 64, \
                                &B_lds[(c) * 16384 + ((ld) * 512 + tid) * 8])
#define WAIT_LGKM0 asm volatile("s_waitcnt lgkmcnt(0)" ::: "memory")
#define WAIT_VM6   asm volatile("s_waitcnt vmcnt(6)"  ::: "memory")
#define WAIT_VM0   asm volatile("s_waitcnt vmcnt(0)"  ::: "memory")

#define READ_AF(p) \
    af[0][0] = *(const bf16x8*)&A_lds[cb + abase + ((p) * 2 + 0) * 1024 + ck0]; \
    af[0][1] = *(const bf16x8*)&A_lds[cb + abase + ((p) * 2 + 0) * 1024 + ck1]; \
    af[1][0] = *(const bf16x8*)&A_lds[cb + abase + ((p) * 2 + 1) * 1024 + ck0]; \
    af[1][1] = *(const bf16x8*)&A_lds[cb + abase + ((p) * 2 + 1) * 1024 + ck1];

#define MFMA_PHASE(p) \
    __builtin_amdgcn_s_setprio(1); \
    if (swap) { \
        _Pragma("unroll") \
        for (int mfi = 0; mfi < 2; ++mfi) \
            _Pragma("unroll") \
            for (int nf = 0; nf < 4; ++nf) { \
                acc[(p) * 2 + mfi][nf] = __builtin_amdgcn_mfma_f32_16x16x32_bf16( \
                    bfrag[nf][0], af[mfi][0], acc[(p) * 2 + mfi][nf], 0, 0, 0); \
                acc[(p) * 2 + mfi][nf] = __builtin_amdgcn_mfma_f32_16x16x32_bf16( \
                    bfrag[nf][1], af[mfi][1], acc[(p) * 2 + mfi][nf], 0, 0, 0); \
            } \
    } else { \
        _Pragma("unroll") \
        for (int mfi = 0; mfi < 2; ++mfi) \
            _Pragma("unroll") \
            for (int nf = 0; nf < 4; ++nf) { \
                acc[(p) * 2 + mfi][nf] = __builtin_amdgcn_mfma_f32_16x16x32_bf16( \
                    af[mfi][0], bfrag[nf][0], acc[(p) * 2 + mfi][nf], 0, 0, 0); \
                acc[(p) * 2 + mfi][nf] = __builtin_amdgcn_mfma_f32_16x16x32_bf16( \
                    af[mfi][1], bfrag[nf][1], acc[(p) * 2 + mfi][nf], 0, 0, 0); \
            } \
    } \
    __builtin_amdgcn_s_setprio(0);

    // ---- prologue ----
    SB(0, 0, 0); SB(1, 0, 0); SB(2, 0, 0); SB(3, 0, 0);
    SA(0, 0, 0); SA(1, 0, 0); SA(2, 0, 0); SA(3, 0, 0);
    SB(0, 1, 1); SB(1, 1, 1); SB(2, 1, 1); SB(3, 1, 1);
    SA(0, 1, 1); SA(2, 1, 1);
    WAIT_VM6;
    __builtin_amdgcn_s_barrier();

    for (int t = 0; t < 16; ++t) {
        const int c = t & 1, o = c ^ 1;
        const int cb = c * 16384;
        bf16x8 bfrag[4][2];
        bf16x8 af[2][2];

        #pragma unroll
        for (int nf = 0; nf < 4; ++nf) {
            bfrag[nf][0] = *(const bf16x8*)&B_lds[cb + bbase + nf * 1024 + ck0];
            bfrag[nf][1] = *(const bf16x8*)&B_lds[cb + bbase + nf * 1024 + ck1];
        }
        READ_AF(0);
        if (t < 15) { SA(1, t + 1, o); SA(3, t + 1, o); }
        __builtin_amdgcn_s_barrier();
        WAIT_LGKM0; __builtin_amdgcn_sched_barrier(0);
        MFMA_PHASE(0);
        __builtin_amdgcn_s_barrier();

        READ_AF(1);
        if (t < 14) { SB(0, t + 2, c); SB(1, t + 2, c);
                      SB(2, t + 2, c); SB(3, t + 2, c); }
        __builtin_amdgcn_s_barrier();
        WAIT_LGKM0; __builtin_amdgcn_sched_barrier(0);
        MFMA_PHASE(1);
        __builtin_amdgcn_s_barrier();

        READ_AF(2);
        if (t < 14) { SA(0, t + 2, c); SA(2, t + 2, c); }
        __builtin_amdgcn_s_barrier();
        WAIT_LGKM0; __builtin_amdgcn_sched_barrier(0);
        MFMA_PHASE(2);

        READ_AF(3);
        __builtin_amdgcn_s_barrier();
        WAIT_LGKM0; __builtin_amdgcn_sched_barrier(0);
        MFMA_PHASE(3);

        if (t < 14)       { WAIT_VM6; __builtin_amdgcn_s_barrier(); }
        else if (t == 14) { WAIT_VM0; __builtin_amdgcn_s_barrier(); }
    }

    // ---- epilogue ----
    const int rb = quad * 4;
    if (MODE == 1) {
        #pragma unroll
        for (int mf = 0; mf < 8; ++mf) {
            const int m = m0 + wr * 128 + mf * 16 + fr;
            if (m < NROWS) {
                #pragma unroll
                for (int nf = 0; nf < 4; ++nf) {
                    const int o_ = n0 + wc * 64 + nf * 16 + rb;
                    float4 pk;
                    pk.x = acc[mf][nf][0];
                    pk.y = acc[mf][nf][1];
                    pk.z = acc[mf][nf][2];
                    pk.w = acc[mf][nf][3];
                    *(float4*)(Out + (long)m * DIMC + o_) = pk;
                }
            }
        }
    } else if (swap) {
        // Q/K: fused RMSNorm + RoPE; weight-folded cos/sin staged to LDS.
        const int part   = n0 >> 10;                 // 0 = Q, 1 = K
        const int hgbase = ((n0 & 1023) + wc * 64) >> 6;
        const float* wtab = (part == 0) ? nqw : nkw;

        float* T = (float*)SMEM;
        __syncthreads();
        for (int e = tid; e < 256 * 16; e += 512) {
            const int row = e >> 4, seg = e & 15;
            const int mm  = m0 + row;
            const int bb2 = mm / NTOK;
            const int n2  = mm - bb2 * NTOK;
            const float4 c4 = *(const float4*)(cosb + n2 * 64 + seg * 4);
            const float4 s4 = *(const float4*)(sinb + n2 * 64 + seg * 4);
            const float4 wf = *(const float4*)(wtab + seg * 4);
            const float4 wp = *(const float4*)(wtab + ((seg ^ 8) * 4));
            float* dst = T + row * 132 + seg * 8;
            ((float2*)dst)[0] = make_float2(c4.x * wf.x, s4.x * wp.x);
            ((float2*)dst)[1] = make_float2(c4.y * wf.y, s4.y * wp.y);
            ((float2*)dst)[2] = make_float2(c4.z * wf.z, s4.z * wp.z);
            ((float2*)dst)[3] = make_float2(c4.w * wf.w, s4.w * wp.w);
        }
        __syncthreads();

#define QK_NF(MF, NF, PN, SGN) { \
        const float4 q0 = *(const float4*)(trow + ((NF) * 16 + rb) * 2); \
        const float4 q1 = *(const float4*)(trow + ((NF) * 16 + rb) * 2 + 4); \
        ushort4 pk; \
        pk.x = f2bf(rms * (acc[MF][NF][0] * q0.x + (SGN) * acc[MF][PN][0] * q0.y)); \
        pk.y = f2bf(rms * (acc[MF][NF][1] * q0.z + (SGN) * acc[MF][PN][1] * q0.w)); \
        pk.z = f2bf(rms * (acc[MF][NF][2] * q1.x + (SGN) * acc[MF][PN][2] * q1.y)); \
        pk.w = f2bf(rms * (acc[MF][NF][3] * q1.z + (SGN) * acc[MF][PN][3] * q1.w)); \
        *(ushort4*)(outb + (NF) * 16) = pk; }

#define QK_MF(MF) { \
        const int rr = wr * 128 + (MF) * 16 + fr; \
        const int m  = m0 + rr; \
        if (m < NROWS) { \
            const int bb = m / NTOK, n = m - bb * NTOK; \
            float ss = 0.f; \
            _Pragma("unroll") \
            for (int nf = 0; nf < 4; ++nf) { \
                ss += acc[MF][nf][0] * acc[MF][nf][0]; \
                ss += acc[MF][nf][1] * acc[MF][nf][1]; \
                ss += acc[MF][nf][2] * acc[MF][nf][2]; \
                ss += acc[MF][nf][3] * acc[MF][nf][3]; \
            } \
            ss += __shfl_xor(ss, 16, 64); \
            ss += __shfl_xor(ss, 32, 64); \
            const float rms = rsqrtf(ss * (1.0f / 64.0f) + 1e-6f); \
            const float* trow = T + rr * 132; \
            ushort_t* outb = QKV + (long)part * QKV_ELEMS + \
                ((long)(bb * 16 + hgbase) * NTOK + n) * 64 + rb; \
            QK_NF(MF, 0, 2, -1.f) \
            QK_NF(MF, 1, 3, -1.f) \
            QK_NF(MF, 2, 0,  1.f) \
            QK_NF(MF, 3, 1,  1.f) \
        } }

        QK_MF(0) QK_MF(1) QK_MF(2) QK_MF(3)
        QK_MF(4) QK_MF(5) QK_MF(6) QK_MF(7)
#undef QK_MF
#undef QK_NF
    } else {
        // V -> Vt[bh][d][n] (dim-major)
        const int hg = ((n0 & 1023) + wc * 64) >> 6;
        #pragma unroll
        for (int nf = 0; nf < 4; ++nf) {
            const int d = nf * 16 + fr;
            #pragma unroll
            for (int mf = 0; mf < 8; ++mf) {
                const int mb = m0 + wr * 128 + mf * 16 + rb;
                if (mb < NROWS) {
                    const int bb = mb / NTOK, n = mb - bb * NTOK;
                    ushort4 pk;
                    pk.x = f2bf(acc[mf][nf][0]);
                    pk.y = f2bf(acc[mf][nf][1]);
                    pk.z = f2bf(acc[mf][nf][2]);
                    pk.w = f2bf(acc[mf][nf][3]);
                    *(ushort4*)(QKV + 2L * QKV_ELEMS +
                        ((long)((bb * 16 + hg) * 64 + d)) * NTOK + n) = pk;
                }
            }
        }
    }
#undef SA
#undef SB
#undef WAIT_LGKM0
#undef WAIT_VM6
#undef WAIT_VM0
#undef READ_AF
#undef MFMA_PHASE
}

__global__ __launch_bounds__(512, 2) void gemm_qkv_kernel(
    const ushort_t* __restrict__ A, const ushort_t* __restrict__ W,
    ushort_t* __restrict__ QKV,
    const float* __restrict__ cosb, const float* __restrict__ sinb,
    const float* __restrict__ nqw, const float* __restrict__ nkw)
{
    gemm256_body<0>(A, W, QKV, nullptr, cosb, sinb, nqw, nkw);
}

__global__ __launch_bounds__(512, 2) void gemm_out_kernel(
    const ushort_t* __restrict__ A, const ushort_t* __restrict__ W,
    float* __restrict__ Out)
{
    gemm256_body<1>(A, W, nullptr, Out, nullptr, nullptr, nullptr, nullptr);
}

// ---------------------------------------------------------------------------
// Merged attention v3 (round 8). Patch path: K AND V staged into LDS via
// COALESCED copies (round-6/7 direct loads were per-lane scattered: each
// bf16x8 fragment load = ~16 cache-line transactions; staging converts that
// to 4-transaction coalesced loads + conflict-tuned LDS reads). Separate
// Ks/Vs/Ps regions -> no buffer overlay -> exactly 2 barriers.
//   Ks[232][68]  stride 68 elem (136B = 34 dw = 2 mod 32 -> 16-bank spread)
//   Vs[64][236]  stride 236 elem (472B = 118 dw = 22 mod 32 -> 16-bank)
//   Ps[32][280]  stride 280 (as before)
//   total 77.8 KB -> 2 blocks/CU. Special path (blocks 0..127) unchanged,
//   uses Ps only.
// ---------------------------------------------------------------------------
__global__ __launch_bounds__(256) void attn_kernel(
    const ushort_t* __restrict__ Qb, const ushort_t* __restrict__ Kb,
    const ushort_t* __restrict__ Vt, ushort_t* __restrict__ AO)
{
    __shared__ __align__(16) ushort_t Ks[232 * 68];
    __shared__ __align__(16) ushort_t Vs[64 * 236];
    __shared__ __align__(16) ushort_t Ps[32 * 280];

    const int tid = threadIdx.x;
    const int wave = tid >> 6, lane = tid & 63;
    const int m_ = lane & 15, quad = lane >> 4;
    const int nb = wave * 64;
    const int d0 = wave * 16;

    bf16x8 ones;
    #pragma unroll
    for (int e = 0; e < 8; ++e) ones[e] = (__bf16)1.0f;

    if (blockIdx.x >= 128) {
        // ================= PATCH =================
        const int blk = blockIdx.x - 128;
        const int bh = blk & 127, qr = blk >> 7;
        const int b = bh >> 4, h = bh & 15;

        int r0 = qr - 3; if (r0 < 0) r0 = 0;
        int r1 = qr + 3; if (r1 > 31) r1 = 31;
        const int limit = 8 + (r1 - r0 + 1) * 32;   // <= 232, multiple of 8
        const int nch = limit >> 3;                  // V chunks per row

        const ushort_t* Qg  = Qb + ((long)bh * NTOK + 8 + qr * 32) * 64;
        const ushort_t* Kg  = Kb + (long)bh * NTOK * 64;
        const ushort_t* Vtg = Vt + (long)bh * 64 * NTOK;

        bf16x8 af[2][2];
        #pragma unroll
        for (int mt = 0; mt < 2; ++mt)
            #pragma unroll
            for (int ks = 0; ks < 2; ++ks)
                af[mt][ks] = *(const bf16x8*)(Qg + (mt * 16 + m_) * 64 + ks * 32 + quad * 8);

        // ---- stage K (coalesced): slot s -> tok = s + (s>=8 ? r0*32 : 0) ----
        for (int c = tid; c < limit * 8; c += 256) {
            const int slot = c >> 3, c8 = (c & 7) * 8;
            const int tok = slot + (slot >= 8 ? r0 * 32 : 0);
            *(bf16x8*)&Ks[slot * 68 + c8] = *(const bf16x8*)(Kg + (long)tok * 64 + c8);
        }
        // ---- stage V (coalesced): Vs[d][col], col==slot mapping ----
        for (int e = tid; e < 64 * 32; e += 256) {
            const int d = e >> 5, j = e & 31;
            if (j < nch) {
                const int tok = (j == 0) ? 0 : 8 + r0 * 32 + (j - 1) * 8;
                *(bf16x8*)&Vs[d * 236 + j * 8] =
                    *(const bf16x8*)(Vtg + (long)d * NTOK + tok);
            }
        }
        __syncthreads();                           // barrier 1: K,V staged

        // ---- QK^T from LDS ----
        bf16x8 bfr[4][2];
        #pragma unroll
        for (int nt = 0; nt < 4; ++nt) {
            const int slot = nb + nt * 16 + m_;
            const int srow = (slot < limit) ? slot : 0;
            #pragma unroll
            for (int ks = 0; ks < 2; ++ks)
                bfr[nt][ks] = *(const bf16x8*)&Ks[srow * 68 + ks * 32 + quad * 8];
        }

        f32x4 sacc[2][4] = {};
        #pragma unroll
        for (int mt = 0; mt < 2; ++mt)
            #pragma unroll
            for (int nt = 0; nt < 4; ++nt) {
                sacc[mt][nt] = __builtin_amdgcn_mfma_f32_16x16x32_bf16(
                    af[mt][0], bfr[nt][0], sacc[mt][nt], 0, 0, 0);
                sacc[mt][nt] = __builtin_amdgcn_mfma_f32_16x16x32_bf16(
                    af[mt][1], bfr[nt][1], sacc[mt][nt], 0, 0, 0);
            }

        #pragma unroll
        for (int mt = 0; mt < 2; ++mt)
            #pragma unroll
            for (int nt = 0; nt < 4; ++nt) {
                const int slot = nb + nt * 16 + m_;
                const int kc = (slot - 8) & 31;
                #pragma unroll
                for (int reg = 0; reg < 4; ++reg) {
                    const int qm = mt * 16 + quad * 4 + reg;
                    const bool val = (slot < 8) ||
                        ((slot < limit) && ((unsigned)(kc - qm + 3) <= 6u));
                    const float p = val ? __expf(sacc[mt][nt][reg] * 0.125f) : 0.f;
                    Ps[qm * 280 + slot] = f2bf(p);
                }
            }
        __syncthreads();                           // barrier 2: P visible

        // ---- PV from LDS (ap and bv both LDS reads) ----
        f32x4 oacc[2] = {}, lacc[2] = {};
        #pragma unroll
        for (int ks = 0; ks < 8; ++ks) {
            const int slot0 = ks * 32 + quad * 8;
            const int col0 = (slot0 < limit) ? slot0 : 0;
            const bf16x8 bv = *(const bf16x8*)&Vs[(d0 + m_) * 236 + col0];
            #pragma unroll
            for (int mt = 0; mt < 2; ++mt) {
                const bf16x8 ap = *(const bf16x8*)&Ps[(mt * 16 + m_) * 280 + ks * 32 + quad * 8];
                oacc[mt] = __builtin_amdgcn_mfma_f32_16x16x32_bf16(ap, bv, oacc[mt], 0, 0, 0);
                lacc[mt] = __builtin_amdgcn_mfma_f32_16x16x32_bf16(ap, ones, lacc[mt], 0, 0, 0);
            }
        }
        #pragma unroll
        for (int mt = 0; mt < 2; ++mt)
            #pragma unroll
            for (int reg = 0; reg < 4; ++reg) {
                const int qm = mt * 16 + quad * 4 + reg;
                const int tok = 8 + qr * 32 + qm;
                AO[((long)(b * NTOK + tok)) * DIMC + h * 64 + d0 + m_] =
                    f2bf(oacc[mt][reg] / lacc[mt][reg]);
            }
    } else {
        // ================= SPECIAL =================
        const int bh = blockIdx.x;
        const int b = bh >> 4, h = bh & 15;
        const ushort_t* Kg  = Kb + (long)bh * NTOK * 64;
        const ushort_t* Vtg = Vt + (long)bh * 64 * NTOK;

        bf16x8 afs[2];
        if (m_ < 8) {
            #pragma unroll
            for (int ks = 0; ks < 2; ++ks)
                afs[ks] = *(const bf16x8*)(Qb + ((long)bh * NTOK + m_) * 64 + ks * 32 + quad * 8);
        } else {
            #pragma unroll
            for (int ks = 0; ks < 2; ++ks)
                #pragma unroll
                for (int e = 0; e < 8; ++e) afs[ks][e] = (__bf16)0.f;
        }

        f32x4 oacc = {}, lacc = {};
        for (int ch = 0; ch < 5; ++ch) {
            const int tok0 = ch * 256;
            const int limit = (NTOK - tok0 < 256) ? (NTOK - tok0) : 256;

            bf16x8 bfr[4][2];
            #pragma unroll
            for (int nt = 0; nt < 4; ++nt) {
                const int slot = nb + nt * 16 + m_;
                const int tok = tok0 + ((slot < limit) ? slot : 0);
                #pragma unroll
                for (int ks = 0; ks < 2; ++ks)
                    bfr[nt][ks] = *(const bf16x8*)(Kg + (long)tok * 64 + ks * 32 + quad * 8);
            }
            f32x4 sacc[4] = {};
            #pragma unroll
            for (int nt = 0; nt < 4; ++nt) {
                sacc[nt] = __builtin_amdgcn_mfma_f32_16x16x32_bf16(afs[0], bfr[nt][0], sacc[nt], 0, 0, 0);
                sacc[nt] = __builtin_amdgcn_mfma_f32_16x16x32_bf16(afs[1], bfr[nt][1], sacc[nt], 0, 0, 0);
            }

            bf16x8 bv[8];
            #pragma unroll
            for (int ks = 0; ks < 8; ++ks) {
                const int slot0 = ks * 32 + quad * 8;
                const int tok = tok0 + ((slot0 < limit) ? slot0 : 0);
                bv[ks] = *(const bf16x8*)(Vtg + (long)(d0 + m_) * NTOK + tok);
            }

            __syncthreads();                  // previous chunk's PV reads done
            #pragma unroll
            for (int nt = 0; nt < 4; ++nt) {
                const int slot = nb + nt * 16 + m_;
                const bool val = (slot < limit);
                #pragma unroll
                for (int reg = 0; reg < 4; ++reg) {
                    const int qm = quad * 4 + reg;
                    const float p = val ? __expf(sacc[nt][reg] * 0.125f) : 0.f;
                    Ps[qm * 280 + slot] = f2bf(p);
                }
            }
            __syncthreads();                  // P visible

            #pragma unroll
            for (int ks = 0; ks < 8; ++ks) {
                const bf16x8 ap = *(const bf16x8*)&Ps[m_ * 280 + ks * 32 + quad * 8];
                oacc = __builtin_amdgcn_mfma_f32_16x16x32_bf16(ap, bv[ks], oacc, 0, 0, 0);
                lacc = __builtin_amdgcn_mfma_f32_16x16x32_bf16(ap, ones,   lacc, 0, 0, 0);
            }
        }

        #pragma unroll
        for (int reg = 0; reg < 4; ++reg) {
            const int qm = quad * 4 + reg;
            if (qm < 8) {
                AO[((long)(b * NTOK + qm)) * DIMC + h * 64 + d0 + m_] =
                    f2bf(oacc[reg] / lacc[reg]);
            }
        }
    }
}

extern "C" void kernel_launch(void* const* d_in, const int* in_sizes, int n_in,
                              void* d_out, int out_size, void* d_ws, size_t ws_size,
                              hipStream_t stream) {
    const float* X    = (const float*)d_in[0];
    const float* fc   = (const float*)d_in[1];
    const float* fs   = (const float*)d_in[2];
    const float* qkvw = (const float*)d_in[3];
    const float* outw = (const float*)d_in[4];
    const float* nqw  = (const float*)d_in[5];
    const float* nkw  = (const float*)d_in[6];

    ushort_t* Qb  = (ushort_t*)d_ws;
    ushort_t* Kb  = Qb + QKV_ELEMS;
    ushort_t* Vt  = Kb + QKV_ELEMS;
    ushort_t* AO  = Vt + QKV_ELEMS;
    ushort_t* Xb  = AO + QKV_ELEMS;
    ushort_t* Wqb = Xb + XE;
    ushort_t* Wob = Wqb + QWE;
    float* Out = (float*)d_out;

    cvt_kernel<<<6176, 256, 0, stream>>>(X, qkvw, outw, Xb, Wqb, Wob);
    gemm_qkv_kernel<<<dim3(12, 33), 512, 0, stream>>>(Xb, Wqb, Qb, fc, fs, nqw, nkw);
    attn_kernel<<<4224, 256, 0, stream>>>(Qb, Kb, Vt, AO);
    gemm_out_kernel<<<dim3(4, 33), 512, 0, stream>>>(AO, Wob, Out);
}

// Round 9
// 250.585 us; speedup vs baseline: 1.0921x; 1.0921x over previous
//
#include <hip/hip_runtime.h>
#include <hip/hip_bf16.h>

typedef unsigned short ushort_t;
typedef __bf16 bf16x8 __attribute__((ext_vector_type(8)));
typedef float f32x4 __attribute__((ext_vector_type(4)));
typedef float f32x8 __attribute__((ext_vector_type(8)));

#define NTOK 1032
#define NROWS 8256       // B*N = 8*1032
#define DIMC 1024
#define QKV_ELEMS 8454144  // 8*16*1032*64 elements per tensor
#define XE 8454144         // X elements (8256*1024)
#define QWE 3145728        // qkv_w elements (3072*1024)
#define OWE 1048576        // out_w elements (1024*1024)

__device__ __forceinline__ float bf2f(ushort_t u) {
    union { unsigned int i; float f; } v; v.i = ((unsigned int)u) << 16; return v.f;
}
__device__ __forceinline__ ushort_t f2bf(float f) {
    union { float f; unsigned int i; } v; v.f = f;
    unsigned int r = v.i + 0x7fffu + ((v.i >> 16) & 1u);
    return (ushort_t)(r >> 16);
}
__device__ __forceinline__ bf16x8 cvt8(const float* p) {
    const float4 a = *(const float4*)p;
    const float4 b = *(const float4*)(p + 4);
    bf16x8 r;
    r[0] = (__bf16)a.x; r[1] = (__bf16)a.y; r[2] = (__bf16)a.z; r[3] = (__bf16)a.w;
    r[4] = (__bf16)b.x; r[5] = (__bf16)b.y; r[6] = (__bf16)b.z; r[7] = (__bf16)b.w;
    return r;
}
__device__ __forceinline__ void load_lds16(const ushort_t* g, ushort_t* l) {
    __builtin_amdgcn_global_load_lds(
        (const __attribute__((address_space(1))) unsigned int*)g,
        (__attribute__((address_space(3))) unsigned int*)l, 16, 0, 0);
}

// ---------------------------------------------------------------------------
// fp32 -> bf16 pre-conversion of X, qkv_w, out_w (RNE).
// ---------------------------------------------------------------------------
__global__ __launch_bounds__(256) void cvt_kernel(
    const float* __restrict__ X, const float* __restrict__ Wq,
    const float* __restrict__ Wo,
    ushort_t* __restrict__ Xb, ushort_t* __restrict__ Wqb,
    ushort_t* __restrict__ Wob)
{
    const long i8 = ((long)blockIdx.x * 256 + threadIdx.x) * 8;
    const float* src;
    ushort_t* dst;
    long off;
    if (i8 < XE)            { src = X;  dst = Xb;  off = i8; }
    else if (i8 < XE + QWE) { src = Wq; dst = Wqb; off = i8 - XE; }
    else                    { src = Wo; dst = Wob; off = i8 - XE - QWE; }
    *(bf16x8*)(dst + off) = cvt8(src + off);
}

// ---------------------------------------------------------------------------
// 256x256 deep-pipelined GEMM body (two named kernels for attribution).
//   MODE 0: QKV projection (nx<8 Q/K swapped + fused norm/rope; nx>=8 V->Vt).
//   MODE 1: out-projection (swap always, fp32 float4 stores), grid 4x33.
// ---------------------------------------------------------------------------
template<int MODE>
__device__ __forceinline__ void gemm256_body(
    const ushort_t* __restrict__ A, const ushort_t* __restrict__ W,
    ushort_t* __restrict__ QKV, float* __restrict__ Out,
    const float* __restrict__ cosb, const float* __restrict__ sinb,
    const float* __restrict__ nqw, const float* __restrict__ nkw)
{
    constexpr int SMEM_BYTES = (MODE == 0) ? 135168 : 131072;
    __shared__ __align__(16) unsigned char SMEM[SMEM_BYTES];
    ushort_t* A_lds = (ushort_t*)SMEM;              // 2 buf x 256 x 64 (64KB)
    ushort_t* B_lds = (ushort_t*)(SMEM + 65536);    // 64KB

    // ---- bijective XCD chunked swizzle (m204) ----
    constexpr int GX  = (MODE == 0) ? 12 : 4;
    constexpr int NWG = GX * 33;
    constexpr int QW  = NWG >> 3, RW = NWG & 7;
    const int orig = blockIdx.y * GX + blockIdx.x;
    const int xcd  = orig & 7, li = orig >> 3;
    const int wgid = (xcd < RW ? xcd * (QW + 1)
                               : RW * (QW + 1) + (xcd - RW) * QW) + li;
    const int bx = wgid % GX, by = wgid / GX;

    const int tid  = threadIdx.x;
    const int wave = tid >> 6, lane = tid & 63;
    const int wr = wave >> 2, wc = wave & 3;        // 2 x 4 wave grid
    const int fr = lane & 15, quad = lane >> 4;
    const int m0 = by * 256;
    const int n0 = bx * 256;
    const bool swap = (MODE == 1) || (bx < 8);

    int aoff[4], boff[4];
    #pragma unroll
    for (int ld = 0; ld < 4; ++ld) {
        const int s   = ld * 512 + tid;
        const int row = s >> 3;
        const int kc  = ((s & 7) ^ (row & 7)) * 8;
        int ar = m0 + row; if (ar > NROWS - 1) ar = NROWS - 1;
        aoff[ld] = ar * DIMC + kc;
        boff[ld] = (n0 + row) * DIMC + kc;
    }

    const int ck0 = (quad ^ (fr & 7)) * 8;          // k-sub 0 (k 0..31)
    const int ck1 = ((quad + 4) ^ (fr & 7)) * 8;    // k-sub 1 (k 32..63)
    const int abase = (wr * 128 + fr) * 64;
    const int bbase = (wc * 64 + fr) * 64;

    f32x4 acc[8][4] = {};

#define SA(ld, t, c) load_lds16(A + aoff[ld] + (t) * 64, \
                                &A_lds[(c) * 16384 + ((ld) * 512 + tid) * 8])
#define SB(ld, t, c) load_lds16(W + boff[ld] + (t) * 64, \
                                &B_lds[(c) * 16384 + ((ld) * 512 + tid) * 8])
#define WAIT_LGKM0 asm volatile("s_waitcnt lgkmcnt(0)" ::: "memory")
#define WAIT_VM6   asm volatile("s_waitcnt vmcnt(6)"  ::: "memory")
#define WAIT_VM0   asm volatile("s_waitcnt vmcnt(0)"  ::: "memory")

#define READ_AF(p) \
    af[0][0] = *(const bf16x8*)&A_lds[cb + abase + ((p) * 2 + 0) * 1024 + ck0]; \
    af[0][1] = *(const bf16x8*)&A_lds[cb + abase + ((p) * 2 + 0) * 1024 + ck1]; \
    af[1][0] = *(const bf16x8*)&A_lds[cb + abase + ((p) * 2 + 1) * 1024 + ck0]; \
    af[1][1] = *(const bf16x8*)&A_lds[cb + abase + ((p) * 2 + 1) * 1024 + ck1];

#define MFMA_PHASE(p) \
    __builtin_amdgcn_s_setprio(1); \
    if (swap) { \
        _Pragma("unroll") \
        for (int mfi = 0; mfi < 2; ++mfi) \
            _Pragma("unroll") \
            for (int nf = 0; nf < 4; ++nf) { \
                acc[(p) * 2 + mfi][nf] = __builtin_amdgcn_mfma_f32_16x16x32_bf16( \
                    bfrag[nf][0], af[mfi][0], acc[(p) * 2 + mfi][nf], 0, 0, 0); \
                acc[(p) * 2 + mfi][nf] = __builtin_amdgcn_mfma_f32_16x16x32_bf16( \
                    bfrag[nf][1], af[mfi][1], acc[(p) * 2 + mfi][nf], 0, 0, 0); \
            } \
    } else { \
        _Pragma("unroll") \
        for (int mfi = 0; mfi < 2; ++mfi) \
            _Pragma("unroll") \
            for (int nf = 0; nf < 4; ++nf) { \
                acc[(p) * 2 + mfi][nf] = __builtin_amdgcn_mfma_f32_16x16x32_bf16( \
                    af[mfi][0], bfrag[nf][0], acc[(p) * 2 + mfi][nf], 0, 0, 0); \
                acc[(p) * 2 + mfi][nf] = __builtin_amdgcn_mfma_f32_16x16x32_bf16( \
                    af[mfi][1], bfrag[nf][1], acc[(p) * 2 + mfi][nf], 0, 0, 0); \
            } \
    } \
    __builtin_amdgcn_s_setprio(0);

    // ---- prologue ----
    SB(0, 0, 0); SB(1, 0, 0); SB(2, 0, 0); SB(3, 0, 0);
    SA(0, 0, 0); SA(1, 0, 0); SA(2, 0, 0); SA(3, 0, 0);
    SB(0, 1, 1); SB(1, 1, 1); SB(2, 1, 1); SB(3, 1, 1);
    SA(0, 1, 1); SA(2, 1, 1);
    WAIT_VM6;
    __builtin_amdgcn_s_barrier();

    for (int t = 0; t < 16; ++t) {
        const int c = t & 1, o = c ^ 1;
        const int cb = c * 16384;
        bf16x8 bfrag[4][2];
        bf16x8 af[2][2];

        #pragma unroll
        for (int nf = 0; nf < 4; ++nf) {
            bfrag[nf][0] = *(const bf16x8*)&B_lds[cb + bbase + nf * 1024 + ck0];
            bfrag[nf][1] = *(const bf16x8*)&B_lds[cb + bbase + nf * 1024 + ck1];
        }
        READ_AF(0);
        if (t < 15) { SA(1, t + 1, o); SA(3, t + 1, o); }
        __builtin_amdgcn_s_barrier();
        WAIT_LGKM0; __builtin_amdgcn_sched_barrier(0);
        MFMA_PHASE(0);
        __builtin_amdgcn_s_barrier();

        READ_AF(1);
        if (t < 14) { SB(0, t + 2, c); SB(1, t + 2, c);
                      SB(2, t + 2, c); SB(3, t + 2, c); }
        __builtin_amdgcn_s_barrier();
        WAIT_LGKM0; __builtin_amdgcn_sched_barrier(0);
        MFMA_PHASE(1);
        __builtin_amdgcn_s_barrier();

        READ_AF(2);
        if (t < 14) { SA(0, t + 2, c); SA(2, t + 2, c); }
        __builtin_amdgcn_s_barrier();
        WAIT_LGKM0; __builtin_amdgcn_sched_barrier(0);
        MFMA_PHASE(2);

        READ_AF(3);
        __builtin_amdgcn_s_barrier();
        WAIT_LGKM0; __builtin_amdgcn_sched_barrier(0);
        MFMA_PHASE(3);

        if (t < 14)       { WAIT_VM6; __builtin_amdgcn_s_barrier(); }
        else if (t == 14) { WAIT_VM0; __builtin_amdgcn_s_barrier(); }
    }

    // ---- epilogue ----
    const int rb = quad * 4;
    if (MODE == 1) {
        #pragma unroll
        for (int mf = 0; mf < 8; ++mf) {
            const int m = m0 + wr * 128 + mf * 16 + fr;
            if (m < NROWS) {
                #pragma unroll
                for (int nf = 0; nf < 4; ++nf) {
                    const int o_ = n0 + wc * 64 + nf * 16 + rb;
                    float4 pk;
                    pk.x = acc[mf][nf][0];
                    pk.y = acc[mf][nf][1];
                    pk.z = acc[mf][nf][2];
                    pk.w = acc[mf][nf][3];
                    *(float4*)(Out + (long)m * DIMC + o_) = pk;
                }
            }
        }
    } else if (swap) {
        // Q/K: fused RMSNorm + RoPE; weight-folded cos/sin staged to LDS.
        const int part   = n0 >> 10;                 // 0 = Q, 1 = K
        const int hgbase = ((n0 & 1023) + wc * 64) >> 6;
        const float* wtab = (part == 0) ? nqw : nkw;

        float* T = (float*)SMEM;
        __syncthreads();
        for (int e = tid; e < 256 * 16; e += 512) {
            const int row = e >> 4, seg = e & 15;
            const int mm  = m0 + row;
            const int bb2 = mm / NTOK;
            const int n2  = mm - bb2 * NTOK;
            const float4 c4 = *(const float4*)(cosb + n2 * 64 + seg * 4);
            const float4 s4 = *(const float4*)(sinb + n2 * 64 + seg * 4);
            const float4 wf = *(const float4*)(wtab + seg * 4);
            const float4 wp = *(const float4*)(wtab + ((seg ^ 8) * 4));
            float* dst = T + row * 132 + seg * 8;
            ((float2*)dst)[0] = make_float2(c4.x * wf.x, s4.x * wp.x);
            ((float2*)dst)[1] = make_float2(c4.y * wf.y, s4.y * wp.y);
            ((float2*)dst)[2] = make_float2(c4.z * wf.z, s4.z * wp.z);
            ((float2*)dst)[3] = make_float2(c4.w * wf.w, s4.w * wp.w);
        }
        __syncthreads();

#define QK_NF(MF, NF, PN, SGN) { \
        const float4 q0 = *(const float4*)(trow + ((NF) * 16 + rb) * 2); \
        const float4 q1 = *(const float4*)(trow + ((NF) * 16 + rb) * 2 + 4); \
        ushort4 pk; \
        pk.x = f2bf(rms * (acc[MF][NF][0] * q0.x + (SGN) * acc[MF][PN][0] * q0.y)); \
        pk.y = f2bf(rms * (acc[MF][NF][1] * q0.z + (SGN) * acc[MF][PN][1] * q0.w)); \
        pk.z = f2bf(rms * (acc[MF][NF][2] * q1.x + (SGN) * acc[MF][PN][2] * q1.y)); \
        pk.w = f2bf(rms * (acc[MF][NF][3] * q1.z + (SGN) * acc[MF][PN][3] * q1.w)); \
        *(ushort4*)(outb + (NF) * 16) = pk; }

#define QK_MF(MF) { \
        const int rr = wr * 128 + (MF) * 16 + fr; \
        const int m  = m0 + rr; \
        if (m < NROWS) { \
            const int bb = m / NTOK, n = m - bb * NTOK; \
            float ss = 0.f; \
            _Pragma("unroll") \
            for (int nf = 0; nf < 4; ++nf) { \
                ss += acc[MF][nf][0] * acc[MF][nf][0]; \
                ss += acc[MF][nf][1] * acc[MF][nf][1]; \
                ss += acc[MF][nf][2] * acc[MF][nf][2]; \
                ss += acc[MF][nf][3] * acc[MF][nf][3]; \
            } \
            ss += __shfl_xor(ss, 16, 64); \
            ss += __shfl_xor(ss, 32, 64); \
            const float rms = rsqrtf(ss * (1.0f / 64.0f) + 1e-6f); \
            const float* trow = T + rr * 132; \
            ushort_t* outb = QKV + (long)part * QKV_ELEMS + \
                ((long)(bb * 16 + hgbase) * NTOK + n) * 64 + rb; \
            QK_NF(MF, 0, 2, -1.f) \
            QK_NF(MF, 1, 3, -1.f) \
            QK_NF(MF, 2, 0,  1.f) \
            QK_NF(MF, 3, 1,  1.f) \
        } }

        QK_MF(0) QK_MF(1) QK_MF(2) QK_MF(3)
        QK_MF(4) QK_MF(5) QK_MF(6) QK_MF(7)
#undef QK_MF
#undef QK_NF
    } else {
        // V -> Vt[bh][d][n] (dim-major)
        const int hg = ((n0 & 1023) + wc * 64) >> 6;
        #pragma unroll
        for (int nf = 0; nf < 4; ++nf) {
            const int d = nf * 16 + fr;
            #pragma unroll
            for (int mf = 0; mf < 8; ++mf) {
                const int mb = m0 + wr * 128 + mf * 16 + rb;
                if (mb < NROWS) {
                    const int bb = mb / NTOK, n = mb - bb * NTOK;
                    ushort4 pk;
                    pk.x = f2bf(acc[mf][nf][0]);
                    pk.y = f2bf(acc[mf][nf][1]);
                    pk.z = f2bf(acc[mf][nf][2]);
                    pk.w = f2bf(acc[mf][nf][3]);
                    *(ushort4*)(QKV + 2L * QKV_ELEMS +
                        ((long)((bb * 16 + hg) * 64 + d)) * NTOK + n) = pk;
                }
            }
        }
    }
#undef SA
#undef SB
#undef WAIT_LGKM0
#undef WAIT_VM6
#undef WAIT_VM0
#undef READ_AF
#undef MFMA_PHASE
}

__global__ __launch_bounds__(512, 2) void gemm_qkv_kernel(
    const ushort_t* __restrict__ A, const ushort_t* __restrict__ W,
    ushort_t* __restrict__ QKV,
    const float* __restrict__ cosb, const float* __restrict__ sinb,
    const float* __restrict__ nqw, const float* __restrict__ nkw)
{
    gemm256_body<0>(A, W, QKV, nullptr, cosb, sinb, nqw, nkw);
}

__global__ __launch_bounds__(512, 2) void gemm_out_kernel(
    const ushort_t* __restrict__ A, const ushort_t* __restrict__ W,
    float* __restrict__ Out)
{
    gemm256_body<1>(A, W, nullptr, Out, nullptr, nullptr, nullptr, nullptr);
}

// ---------------------------------------------------------------------------
// Attention v4 (round 9): WAVE-INDEPENDENT patch path. Diagnosis: patch
// blocks are short serial latency chains; with 4-wave lockstep around the P
// barrier only ~2 tiles/CU are in flight and 4096 blocks run ~16 generations
// deep -> ~85us for ~25us of work. Fix: one WAVE owns one (bh,qr) tile
// end-to-end; P lives in a private per-wave LDS slice [32][264] (stride 264
// elem = 132dw = 4 mod 32 -> 2-way = free); NO __syncthreads in the patch
// path (within-wave ds_write->ds_read needs only lgkmcnt(0), m214 pattern).
// 67.6KB/block -> 2 blocks/CU = 8 independent tiles in flight (4x).
// Patch grid: 1024 blocks x 4 tiles. Special path: old cooperative code
// (128 blocks), stride 280->264. Math and accumulation order bit-identical.
// ---------------------------------------------------------------------------
__global__ __launch_bounds__(256) void attn_kernel(
    const ushort_t* __restrict__ Qb, const ushort_t* __restrict__ Kb,
    const ushort_t* __restrict__ Vt, ushort_t* __restrict__ AO)
{
    __shared__ __align__(16) ushort_t Ps[4 * 32 * 264];   // 67.6 KB

    const int tid = threadIdx.x;
    const int wave = tid >> 6, lane = tid & 63;
    const int m_ = lane & 15, quad = lane >> 4;

    bf16x8 ones;
    #pragma unroll
    for (int e = 0; e < 8; ++e) ones[e] = (__bf16)1.0f;

    if (blockIdx.x >= 128) {
        // ================= PATCH (wave-independent) =================
        const int t4 = (blockIdx.x - 128) * 4 + wave;     // 0..4095
        const int bh = t4 & 127, qr = t4 >> 7;
        const int b = bh >> 4, h = bh & 15;

        int r0 = qr - 3; if (r0 < 0) r0 = 0;
        int r1 = qr + 3; if (r1 > 31) r1 = 31;
        const int limit = 8 + (r1 - r0 + 1) * 32;          // 136..232

        const ushort_t* Qg  = Qb + ((long)bh * NTOK + 8 + qr * 32) * 64;
        const ushort_t* Kg  = Kb + (long)bh * NTOK * 64;
        const ushort_t* Vtg = Vt + (long)bh * 64 * NTOK;
        ushort_t* Pw = Ps + wave * (32 * 264);

        bf16x8 af[2][2];
        #pragma unroll
        for (int mt = 0; mt < 2; ++mt)
            #pragma unroll
            for (int ks = 0; ks < 2; ++ks)
                af[mt][ks] = *(const bf16x8*)(Qg + (mt * 16 + m_) * 64 + ks * 32 + quad * 8);

        // ---- QK^T streamed over 16 slot-tiles; P fully initialized ----
        #pragma unroll
        for (int nt = 0; nt < 16; ++nt) {
            const int slot = nt * 16 + m_;
            if (nt * 16 < limit) {
                int tok = (slot < 8) ? slot : (slot + r0 * 32);
                if (slot >= limit) tok = 0;
                const bf16x8 b0 = *(const bf16x8*)(Kg + (long)tok * 64 + quad * 8);
                const bf16x8 b1 = *(const bf16x8*)(Kg + (long)tok * 64 + 32 + quad * 8);
                f32x4 s0 = {}, s1 = {};
                s0 = __builtin_amdgcn_mfma_f32_16x16x32_bf16(af[0][0], b0, s0, 0, 0, 0);
                s0 = __builtin_amdgcn_mfma_f32_16x16x32_bf16(af[0][1], b1, s0, 0, 0, 0);
                s1 = __builtin_amdgcn_mfma_f32_16x16x32_bf16(af[1][0], b0, s1, 0, 0, 0);
                s1 = __builtin_amdgcn_mfma_f32_16x16x32_bf16(af[1][1], b1, s1, 0, 0, 0);
                const int kc = (slot - 8) & 31;
                #pragma unroll
                for (int reg = 0; reg < 4; ++reg) {
                    const int qm0 = quad * 4 + reg;
                    const bool v0 = (slot < 8) ||
                        ((slot < limit) && ((unsigned)(kc - qm0 + 3) <= 6u));
                    Pw[qm0 * 264 + slot] = f2bf(v0 ? __expf(s0[reg] * 0.125f) : 0.f);
                    const int qm1 = 16 + qm0;
                    const bool v1 = (slot < 8) ||
                        ((slot < limit) && ((unsigned)(kc - qm1 + 3) <= 6u));
                    Pw[qm1 * 264 + slot] = f2bf(v1 ? __expf(s1[reg] * 0.125f) : 0.f);
                }
            } else {
                #pragma unroll
                for (int reg = 0; reg < 4; ++reg) {
                    const int qm0 = quad * 4 + reg;
                    Pw[qm0 * 264 + slot] = 0;
                    Pw[(16 + qm0) * 264 + slot] = 0;
                }
            }
        }

        asm volatile("s_waitcnt lgkmcnt(0)" ::: "memory");
        __builtin_amdgcn_sched_barrier(0);

        // ---- PV: this wave covers all 64 d ----
        f32x4 oacc[2][4] = {};
        f32x4 lacc[2] = {};
        #pragma unroll
        for (int ks = 0; ks < 8; ++ks) {
            const int slot0 = ks * 32 + quad * 8;
            int tokv;
            if (slot0 >= limit) tokv = 0;
            else if (slot0 < 8) tokv = slot0;
            else tokv = 8 + r0 * 32 + (slot0 - 8);
            const bf16x8 ap0 = *(const bf16x8*)&Pw[(m_) * 264 + slot0];
            const bf16x8 ap1 = *(const bf16x8*)&Pw[(16 + m_) * 264 + slot0];
            #pragma unroll
            for (int db = 0; db < 4; ++db) {
                const bf16x8 bv = *(const bf16x8*)(Vtg + (long)(db * 16 + m_) * NTOK + tokv);
                oacc[0][db] = __builtin_amdgcn_mfma_f32_16x16x32_bf16(ap0, bv, oacc[0][db], 0, 0, 0);
                oacc[1][db] = __builtin_amdgcn_mfma_f32_16x16x32_bf16(ap1, bv, oacc[1][db], 0, 0, 0);
            }
            lacc[0] = __builtin_amdgcn_mfma_f32_16x16x32_bf16(ap0, ones, lacc[0], 0, 0, 0);
            lacc[1] = __builtin_amdgcn_mfma_f32_16x16x32_bf16(ap1, ones, lacc[1], 0, 0, 0);
        }

        #pragma unroll
        for (int mt = 0; mt < 2; ++mt)
            #pragma unroll
            for (int reg = 0; reg < 4; ++reg) {
                const int qm = mt * 16 + quad * 4 + reg;
                const int tok = 8 + qr * 32 + qm;
                const float inv = 1.0f / lacc[mt][reg];
                #pragma unroll
                for (int db = 0; db < 4; ++db) {
                    AO[((long)(b * NTOK + tok)) * DIMC + h * 64 + db * 16 + m_] =
                        f2bf(oacc[mt][db][reg] * inv);
                }
            }
    } else {
        // ================= SPECIAL (cooperative, as before) =================
        const int nb = wave * 64;
        const int d0 = wave * 16;
        const int bh = blockIdx.x;
        const int b = bh >> 4, h = bh & 15;
        const ushort_t* Kg  = Kb + (long)bh * NTOK * 64;
        const ushort_t* Vtg = Vt + (long)bh * 64 * NTOK;

        bf16x8 afs[2];
        if (m_ < 8) {
            #pragma unroll
            for (int ks = 0; ks < 2; ++ks)
                afs[ks] = *(const bf16x8*)(Qb + ((long)bh * NTOK + m_) * 64 + ks * 32 + quad * 8);
        } else {
            #pragma unroll
            for (int ks = 0; ks < 2; ++ks)
                #pragma unroll
                for (int e = 0; e < 8; ++e) afs[ks][e] = (__bf16)0.f;
        }

        f32x4 oacc = {}, lacc = {};
        for (int ch = 0; ch < 5; ++ch) {
            const int tok0 = ch * 256;
            const int limit = (NTOK - tok0 < 256) ? (NTOK - tok0) : 256;

            bf16x8 bfr[4][2];
            #pragma unroll
            for (int nt = 0; nt < 4; ++nt) {
                const int slot = nb + nt * 16 + m_;
                const int tok = tok0 + ((slot < limit) ? slot : 0);
                #pragma unroll
                for (int ks = 0; ks < 2; ++ks)
                    bfr[nt][ks] = *(const bf16x8*)(Kg + (long)tok * 64 + ks * 32 + quad * 8);
            }
            f32x4 sacc[4] = {};
            #pragma unroll
            for (int nt = 0; nt < 4; ++nt) {
                sacc[nt] = __builtin_amdgcn_mfma_f32_16x16x32_bf16(afs[0], bfr[nt][0], sacc[nt], 0, 0, 0);
                sacc[nt] = __builtin_amdgcn_mfma_f32_16x16x32_bf16(afs[1], bfr[nt][1], sacc[nt], 0, 0, 0);
            }

            bf16x8 bv[8];
            #pragma unroll
            for (int ks = 0; ks < 8; ++ks) {
                const int slot0 = ks * 32 + quad * 8;
                const int tok = tok0 + ((slot0 < limit) ? slot0 : 0);
                bv[ks] = *(const bf16x8*)(Vtg + (long)(d0 + m_) * NTOK + tok);
            }

            __syncthreads();                  // previous chunk's PV reads done
            #pragma unroll
            for (int nt = 0; nt < 4; ++nt) {
                const int slot = nb + nt * 16 + m_;
                const bool val = (slot < limit);
                #pragma unroll
                for (int reg = 0; reg < 4; ++reg) {
                    const int qm = quad * 4 + reg;
                    const float p = val ? __expf(sacc[nt][reg] * 0.125f) : 0.f;
                    Ps[qm * 264 + slot] = f2bf(p);
                }
            }
            __syncthreads();                  // P visible

            #pragma unroll
            for (int ks = 0; ks < 8; ++ks) {
                const bf16x8 ap = *(const bf16x8*)&Ps[m_ * 264 + ks * 32 + quad * 8];
                oacc = __builtin_amdgcn_mfma_f32_16x16x32_bf16(ap, bv[ks], oacc, 0, 0, 0);
                lacc = __builtin_amdgcn_mfma_f32_16x16x32_bf16(ap, ones,   lacc, 0, 0, 0);
            }
        }

        #pragma unroll
        for (int reg = 0; reg < 4; ++reg) {
            const int qm = quad * 4 + reg;
            if (qm < 8) {
                AO[((long)(b * NTOK + qm)) * DIMC + h * 64 + d0 + m_] =
                    f2bf(oacc[reg] / lacc[reg]);
            }
        }
    }
}

extern "C" void kernel_launch(void* const* d_in, const int* in_sizes, int n_in,
                              void* d_out, int out_size, void* d_ws, size_t ws_size,
                              hipStream_t stream) {
    const float* X    = (const float*)d_in[0];
    const float* fc   = (const float*)d_in[1];
    const float* fs   = (const float*)d_in[2];
    const float* qkvw = (const float*)d_in[3];
    const float* outw = (const float*)d_in[4];
    const float* nqw  = (const float*)d_in[5];
    const float* nkw  = (const float*)d_in[6];

    ushort_t* Qb  = (ushort_t*)d_ws;
    ushort_t* Kb  = Qb + QKV_ELEMS;
    ushort_t* Vt  = Kb + QKV_ELEMS;
    ushort_t* AO  = Vt + QKV_ELEMS;
    ushort_t* Xb  = AO + QKV_ELEMS;
    ushort_t* Wqb = Xb + XE;
    ushort_t* Wob = Wqb + QWE;
    float* Out = (float*)d_out;

    cvt_kernel<<<6176, 256, 0, stream>>>(X, qkvw, outw, Xb, Wqb, Wob);
    gemm_qkv_kernel<<<dim3(12, 33), 512, 0, stream>>>(Xb, Wqb, Qb, fc, fs, nqw, nkw);
    attn_kernel<<<1152, 256, 0, stream>>>(Qb, Kb, Vt, AO);
    gemm_out_kernel<<<dim3(4, 33), 512, 0, stream>>>(AO, Wob, Out);
}